// Round 8
// baseline (314.730 us; speedup 1.0000x reference)
//
#include <hip/hip_runtime.h>

typedef _Float16 half8  __attribute__((ext_vector_type(8)));
typedef float    f32x4  __attribute__((ext_vector_type(4)));
typedef unsigned int u32;

#define QLEN  512
#define NS    64
#define LS    128
#define EDIM  256

// barrier that does NOT drain vmcnt: LDS writes visible, global loads stay in flight
__device__ __forceinline__ void block_sync_lds() {
    asm volatile("s_waitcnt lgkmcnt(0)" ::: "memory");
    __builtin_amdgcn_s_barrier();
    asm volatile("" ::: "memory");
}

// RNE fp32x8 -> fp16x8 (matches reference-tolerance behavior of earlier rounds)
__device__ __forceinline__ half8 cvt8(f32x4 a, f32x4 b) {
    half8 h;
    h[0]=(_Float16)a[0]; h[1]=(_Float16)a[1]; h[2]=(_Float16)a[2]; h[3]=(_Float16)a[3];
    h[4]=(_Float16)b[0]; h[5]=(_Float16)b[1]; h[6]=(_Float16)b[2]; h[7]=(_Float16)b[3];
    return h;
}

// ---- V global loads: lane (vp,vlh) covers rows l = lt*32+vlh*16+i, cols e = vp, vp+128 ----
// per instr: 64 lanes x 4B contiguous = 256B segments, fully coalesced
#define VLOAD(dL, dH, lt) do {                                                \
  const float* vb0 = vbase + (size_t)((lt) * 32 + vlh * 16) * EDIM + vp;      \
  _Pragma("unroll") for (int i = 0; i < 16; ++i) {                            \
    dL[i] = vb0[(size_t)i * EDIM];                                            \
    dH[i] = vb0[(size_t)i * EDIM + 128]; } } while (0)

// ---- V^T LDS: [256 e][64 l] fp16, 128B rows; col16 = cp*4 + l/8, swizzle ^(e&7) ----
// write quad = (cp*4+u)^(vp&7): 8 quads x 8 lanes = 2-way (free)
#define VSTORE(dL, dH, lt) do {                                               \
  int cp = (lt) & 1;                                                          \
  _Pragma("unroll") for (int jj = 0; jj < 2; ++jj) {                          \
    half8 h0, h1;                                                             \
    _Pragma("unroll") for (int j = 0; j < 8; ++j) {                           \
      h0[j] = (_Float16)dL[jj*8+j]; h1[j] = (_Float16)dH[jj*8+j]; }           \
    int u   = vlh * 2 + jj;                                                   \
    int col = ((cp * 4 + u) ^ (vp & 7)) * 16;                                 \
    *(half8*)(vbuf + (size_t)vp * 128 + col)         = h0;                    \
    *(half8*)(vbuf + (size_t)(vp + 128) * 128 + col) = h1; } } while (0)

// ---- PV: A = V^T frag (LDS), B = P^T frag (exchanged in-register, R5-proven) ----
// read quad = (cp*4+g)^(c&7): 8 quads x 2 lanes = 2-way (free)
#define PV(lt) do {                                                           \
  u32 zx = sel2 ? pk0[2*(lt)+1] : pk0[2*(lt)];                                \
  u32 zy = sel2 ? pk1[2*(lt)+1] : pk1[2*(lt)];                                \
  u32 wx = sel2 ? pk0[2*(lt)]   : pk0[2*(lt)+1];                              \
  u32 wy = sel2 ? pk1[2*(lt)]   : pk1[2*(lt)+1];                              \
  u32 az0 = (u32)__shfl((int)zx, s0, 64), az1 = (u32)__shfl((int)zy, s0, 64); \
  u32 aw0 = (u32)__shfl((int)wx, s0, 64), aw1 = (u32)__shfl((int)wy, s0, 64); \
  u32 bz0 = (u32)__shfl((int)zx, s1, 64), bz1 = (u32)__shfl((int)zy, s1, 64); \
  u32 bw0 = (u32)__shfl((int)wx, s1, 64), bw1 = (u32)__shfl((int)wy, s1, 64); \
  union { u32 u[4]; half8 h; } pf;                                            \
  pf.u[0] = useZ ? az0 : aw0;  pf.u[1] = useZ ? az1 : aw1;                    \
  pf.u[2] = useZ ? bz0 : bw0;  pf.u[3] = useZ ? bz1 : bw1;                    \
  int cp = (lt) & 1;                                                          \
  __builtin_amdgcn_s_setprio(1);                                              \
  _Pragma("unroll") for (int et = 0; et < 16; ++et) {                         \
    int e = et * 16 + c;                                                      \
    half8 vf = *(const half8*)(vbuf + (size_t)e * 128 +                       \
                               (((cp * 4 + g) ^ (e & 7)) * 16));              \
    oacc[et] = __builtin_amdgcn_mfma_f32_16x16x32_f16(vf, pf.h, oacc[et], 0, 0, 0); } \
  __builtin_amdgcn_s_setprio(0); } while (0)

__global__ __launch_bounds__(256, 3)
void DotAttn_20083267076209_kernel(const float* __restrict__ qg,
                                   const float* __restrict__ kg,
                                   const float* __restrict__ vg,
                                   const int*   __restrict__ maskg,
                                   float*       __restrict__ outg)
{
    // LDS: V^T only. [256 e][64 l] fp16 = 32 KB; holds chunk pair (0,1) then (2,3)
    __shared__ __align__(16) unsigned char vbuf[32768];

    const int tid  = threadIdx.x;
    const int lane = tid & 63;
    const int c    = lane & 15;
    const int g    = lane >> 4;
    const int vp   = tid & 127;   // V e-column index (also e+128)
    const int vlh  = tid >> 7;    // V l-half within a 32-l chunk

    const bool sel2 = (g >= 2);
    const bool useZ = (g == 0) || (g == 3);
    const int  s0   = c + ((g & 1) << 5);
    const int  s1   = s0 + 16;
    const int  w    = tid >> 6;

    // XCD-bijective decode: all 8 qt-sharers of (b,s) on the same XCD
    const int bid = blockIdx.x;
    const int xcd = bid & 7;
    const int qt  = (bid >> 3) & 7;
    const int b   = (bid >> 6) & 7;
    const int s   = (bid >> 9) * 8 + xcd;

    const float* kbase = kg + (size_t)(b * NS + s) * LS * EDIM;
    const float* vbase = vg + (size_t)(b * NS + s) * LS * EDIM;
    const float* qbase = qg + ((size_t)b * QLEN + (size_t)qt * 64 + (size_t)w * 16) * EDIM;

    // mask loads first (vmcnt wait for ballot won't drain later loads)
    const int* mb = maskg + (b * NS + s) * LS;
    int mraw0 = mb[lane];
    int mraw1 = mb[64 + lane];

    // V chunk 0 in flight immediately
    float vAL[16], vAH[16], vBL[16], vBH[16];
    VLOAD(vAL, vAH, 0);

    // Q frags (B-operand): lane (c,g) holds Q[q=c][e = ks*32 + g*8 + j]
    half8 qf[8];
#pragma unroll
    for (int ks = 0; ks < 8; ++ks) {
        const float* p = qbase + (size_t)c * EDIM + ks * 32 + g * 8;
        qf[ks] = cvt8(*(const f32x4*)p, *(const f32x4*)(p + 4));
    }

    unsigned long long m0 = __ballot(mraw0 != 0);
    unsigned long long m1 = __ballot(mraw1 != 0);

    // ---- S^T = K Q^T, K fragments DIRECT from global (no LDS, no barriers) ----
    // sacc[t][r] = S^T[l = t*16 + 4g + r][q = c]
    f32x4 sacc[8];
#pragma unroll
    for (int t = 0; t < 8; ++t) sacc[t] = (f32x4){0.f, 0.f, 0.f, 0.f};

#pragma unroll
    for (int lt = 0; lt < 8; ++lt) {
        const float* kp = kbase + (size_t)(lt * 16 + c) * EDIM + g * 8;
        f32x4 ka[8], kb[8];
#pragma unroll
        for (int ks = 0; ks < 8; ++ks) {
            ka[ks] = *(const f32x4*)(kp + ks * 32);
            kb[ks] = *(const f32x4*)(kp + ks * 32 + 4);
        }
        __builtin_amdgcn_s_setprio(1);
#pragma unroll
        for (int ks = 0; ks < 8; ++ks)
            sacc[lt] = __builtin_amdgcn_mfma_f32_16x16x32_f16(cvt8(ka[ks], kb[ks]),
                                                              qf[ks], sacc[lt], 0, 0, 0);
        __builtin_amdgcn_s_setprio(0);
        // V staging interleaved with S-phase (LDS untouched by S -> no barrier needed)
        if (lt == 1) { VSTORE(vAL, vAH, 0); VLOAD(vAL, vAH, 1); }
        if (lt == 5) { VSTORE(vAL, vAH, 1); VLOAD(vAL, vAH, 2); }
    }

    // ---- mask (per-lane l = t*16 + 4g + r) ----
#pragma unroll
    for (int t = 0; t < 8; ++t) {
        unsigned bits = (unsigned)(((t < 4 ? m0 : m1) >> ((t & 3) * 16 + 4 * g)) & 0xFull);
#pragma unroll
        for (int r = 0; r < 4; ++r)
            if (!((bits >> r) & 1)) sacc[t][r] = -1e30f;
    }

    // ---- softmax over l for column q=c: 32 local values + lanes c+16k ----
    {
        float m = sacc[0][0];
#pragma unroll
        for (int t = 0; t < 8; ++t)
#pragma unroll
            for (int r = 0; r < 4; ++r) m = fmaxf(m, sacc[t][r]);
        m = fmaxf(m, __shfl_xor(m, 16, 64));
        m = fmaxf(m, __shfl_xor(m, 32, 64));
        float sum = 0.f;
#pragma unroll
        for (int t = 0; t < 8; ++t)
#pragma unroll
            for (int r = 0; r < 4; ++r) {
                float p = __expf(sacc[t][r] - m);
                sacc[t][r] = p;
                sum += p;
            }
        sum += __shfl_xor(sum, 16, 64);
        sum += __shfl_xor(sum, 32, 64);
        float inv = 1.f / sum;
#pragma unroll
        for (int t = 0; t < 8; ++t)
#pragma unroll
            for (int r = 0; r < 4; ++r) sacc[t][r] *= inv;
    }

    // ---- pack P^T to fp16 pairs (RTZ fine: P in [0,1]) ----
    u32 pk0[8], pk1[8];
#pragma unroll
    for (int t = 0; t < 8; ++t) {
        pk0[t] = __builtin_bit_cast(u32, __builtin_amdgcn_cvt_pkrtz(sacc[t][0], sacc[t][1]));
        pk1[t] = __builtin_bit_cast(u32, __builtin_amdgcn_cvt_pkrtz(sacc[t][2], sacc[t][3]));
    }

    // ---- O^T = V^T P^T : 3 barriers total ----
    f32x4 oacc[16];
#pragma unroll
    for (int et = 0; et < 16; ++et) oacc[et] = (f32x4){0.f, 0.f, 0.f, 0.f};

    block_sync_lds();             // #1: chunks 0,1 staged by all waves
    PV(0);
    VLOAD(vBL, vBH, 3);           // chunk 3 in flight under PV
    PV(1);
    block_sync_lds();             // #2: all waves done reading chunks 0,1
    VSTORE(vAL, vAH, 2);          // overwrites chunk0 cols
    VSTORE(vBL, vBH, 3);          // overwrites chunk1 cols
    block_sync_lds();             // #3: chunks 2,3 staged
    PV(2);
    PV(3);

    // ---- epilogue: out[b][q=qt*64+w*16+c][s][e = et*16 + 4g + r] ----
    float* ob = outg + (((size_t)b * QLEN + (size_t)qt * 64 + w * 16 + c) * NS + s) * EDIM + 4 * g;
#pragma unroll
    for (int et = 0; et < 16; ++et)
        *(f32x4*)(ob + et * 16) = oacc[et];
}

extern "C" void kernel_launch(void* const* d_in, const int* in_sizes, int n_in,
                              void* d_out, int out_size, void* d_ws, size_t ws_size,
                              hipStream_t stream) {
    const float* q    = (const float*)d_in[0];
    const float* k    = (const float*)d_in[1];
    const float* v    = (const float*)d_in[2];
    const int*   mask = (const int*)d_in[3];
    float* out = (float*)d_out;
    dim3 grid(4096);
    dim3 block(256);
    hipLaunchKernelGGL(DotAttn_20083267076209_kernel, grid, block, 0, stream,
                       q, k, v, mask, out);
}